// Round 1
// baseline (405.016 us; speedup 1.0000x reference)
//
#include <hip/hip_runtime.h>
#include <hip/hip_bf16.h>

#define NN 50000
#define NE 800000
#define DD 256
#define KK 512   // concat K for fused GEMM

typedef unsigned short u16;
typedef unsigned int   u32;
typedef __attribute__((ext_vector_type(8))) __bf16 bf16x8;
typedef __attribute__((ext_vector_type(4))) float  f32x4;
typedef __attribute__((ext_vector_type(8))) u16    u16x8;
typedef __attribute__((ext_vector_type(4))) u16    u16x4;

static __device__ __forceinline__ u16 f2bf(float f) {
  u32 u = __float_as_uint(f);
  u32 r = (u + 0x7FFFu + ((u >> 16) & 1u)) >> 16;
  return (u16)r;
}
static __device__ __forceinline__ float bf2f(u16 h) {
  return __uint_as_float(((u32)h) << 16);
}

// ---------------- CSR build ----------------
__global__ void k_histo(const int* __restrict__ tgt, int* __restrict__ deg) {
  int i = blockIdx.x * 256 + threadIdx.x;
  if (i < NE) atomicAdd(&deg[tgt[i]], 1);
}

// single-block exclusive scan over NN degrees -> off[NN+1], cursor[NN]
__global__ void k_scan(const int* __restrict__ deg, int* __restrict__ off,
                       int* __restrict__ cursor) {
  __shared__ int partial[1024];
  const int tid = threadIdx.x;
  const int CH = (NN + 1023) / 1024;  // 49
  int lo = tid * CH, hi = min(lo + CH, NN);
  int s = 0;
  for (int i = lo; i < hi; ++i) s += deg[i];
  partial[tid] = s;
  __syncthreads();
  for (int d = 1; d < 1024; d <<= 1) {
    int v = (tid >= d) ? partial[tid - d] : 0;
    __syncthreads();
    partial[tid] += v;
    __syncthreads();
  }
  int base = (tid == 0) ? 0 : partial[tid - 1];
  for (int i = lo; i < hi; ++i) {
    off[i] = base; cursor[i] = base;
    base += deg[i];
  }
  if (tid == 1023) off[NN] = base;  // == NE
}

__global__ void k_fill(const int* __restrict__ src, const int* __restrict__ tgt,
                       int* __restrict__ cursor, int* __restrict__ col) {
  int i = blockIdx.x * 256 + threadIdx.x;
  if (i < NE) {
    int p = atomicAdd(&cursor[tgt[i]], 1);
    col[p] = src[i];
  }
}

// ---------------- dtype prep ----------------
__global__ void k_f32_to_bf16(const float* __restrict__ in, u16* __restrict__ out, int n4) {
  int i = blockIdx.x * 256 + threadIdx.x;
  if (i >= n4) return;
  const float4 v = *reinterpret_cast<const float4*>(in + i * 4);
  u16x4 o; o.x = f2bf(v.x); o.y = f2bf(v.y); o.z = f2bf(v.z); o.w = f2bf(v.w);
  *reinterpret_cast<u16x4*>(out + i * 4) = o;
}

// WcT[n][k] (bf16, [256][512]): k<256 -> Wl[k][n], else Wr[k-256][n]
__global__ void k_make_wcT(const float* __restrict__ Wl, const float* __restrict__ Wr,
                           u16* __restrict__ WcT) {
  int idx = blockIdx.x * 256 + threadIdx.x;  // 131072 total
  int n = idx >> 9, k = idx & 511;
  float v = (k < DD) ? Wl[k * DD + n] : Wr[(k - DD) * DD + n];
  WcT[idx] = f2bf(v);
}

// ---------------- mean aggregation (CSR) ----------------
// one wave per target node; lane handles 4 contiguous features
__global__ void k_aggregate(const u16* __restrict__ feat, const int* __restrict__ off,
                            const int* __restrict__ col, u16* __restrict__ out) {
  const int wave = threadIdx.x >> 6;
  const int lane = threadIdx.x & 63;
  const int node = blockIdx.x * 4 + wave;
  const int s = off[node], e = off[node + 1];
  const int fo = lane * 4;
  float a0 = 0.f, a1 = 0.f, a2 = 0.f, a3 = 0.f;
  int nxt = (s < e) ? col[s] : 0;
  for (int i = s; i < e; ++i) {
    int cur = nxt;
    if (i + 1 < e) nxt = col[i + 1];
    u16x4 v = *reinterpret_cast<const u16x4*>(feat + cur * DD + fo);
    a0 += bf2f(v.x); a1 += bf2f(v.y); a2 += bf2f(v.z); a3 += bf2f(v.w);
  }
  const float scale = (e > s) ? 1.0f / (float)(e - s) : 0.0f;
  u16x4 o;
  o.x = f2bf(a0 * scale); o.y = f2bf(a1 * scale);
  o.z = f2bf(a2 * scale); o.w = f2bf(a3 * scale);
  *reinterpret_cast<u16x4*>(out + node * DD + fo) = o;
}

// ---------------- fused GEMM: out = [A0|A1] @ Wc + bias (+relu) ----------------
// A0 = agg (M x 256 bf16), A1 = x or h (M x 256 bf16), WcT = (256 x 512 bf16, [n][k])
// LAYER==1: relu, bf16 out; LAYER==2: f32 out
#define BM 128
#define BN 128
#define BK 64

template <int LAYER>
__global__ void k_gemm_fused(const u16* __restrict__ A0, const u16* __restrict__ A1,
                             const u16* __restrict__ WcT, const float* __restrict__ bias,
                             u16* __restrict__ outb, float* __restrict__ outf, int M) {
  __shared__ alignas(16) u16 lA[BM * BK];
  __shared__ alignas(16) u16 lB[BN * BK];
  const int tid = threadIdx.x;
  const int rowBase = blockIdx.x * BM;
  const int colBase = blockIdx.y * BN;
  const int wave = tid >> 6, lane = tid & 63;
  const int wr = wave >> 1, wc = wave & 1;  // 2x2 waves, 64x64 each

  f32x4 acc[4][4] = {};

  const int sr = tid >> 3;          // 0..31 staging row within 32-row group
  const int sc = (tid & 7) * 8;     // bf16 col offset 0..56

  for (int k0 = 0; k0 < KK; k0 += BK) {
    if (k0) __syncthreads();
    const u16* Asrc = (k0 < DD) ? A0 : A1;
    const int kk = k0 & (DD - 1);
    // stage A: 128 x 64 bf16 (XOR-swizzled rows)
#pragma unroll
    for (int it = 0; it < 4; ++it) {
      int row = it * 32 + sr;
      int grow = rowBase + row;
      int gr = (grow < M) ? grow : 0;
      u16x8 v = *reinterpret_cast<const u16x8*>(Asrc + gr * DD + kk + sc);
      int kb = (sc * 2) ^ ((row & 7) << 4);
      *reinterpret_cast<u16x8*>((char*)lA + row * 128 + kb) = v;
    }
    // stage B (BT[n][k]): 128 x 64 bf16
#pragma unroll
    for (int it = 0; it < 4; ++it) {
      int row = it * 32 + sr;  // n within tile
      u16x8 v = *reinterpret_cast<const u16x8*>(WcT + (colBase + row) * KK + k0 + sc);
      int kb = (sc * 2) ^ ((row & 7) << 4);
      *reinterpret_cast<u16x8*>((char*)lB + row * 128 + kb) = v;
    }
    __syncthreads();

#pragma unroll
    for (int ks = 0; ks < 2; ++ks) {
      const int kbyte = ks * 64 + (lane >> 4) * 16;
      bf16x8 af[4], bfg[4];
#pragma unroll
      for (int m = 0; m < 4; ++m) {
        int row = wr * 64 + m * 16 + (lane & 15);
        af[m] = *reinterpret_cast<const bf16x8*>((const char*)lA + row * 128 + (kbyte ^ ((row & 7) << 4)));
      }
#pragma unroll
      for (int n = 0; n < 4; ++n) {
        int row = wc * 64 + n * 16 + (lane & 15);
        bfg[n] = *reinterpret_cast<const bf16x8*>((const char*)lB + row * 128 + (kbyte ^ ((row & 7) << 4)));
      }
#pragma unroll
      for (int m = 0; m < 4; ++m)
#pragma unroll
        for (int n = 0; n < 4; ++n)
          acc[m][n] = __builtin_amdgcn_mfma_f32_16x16x32_bf16(af[m], bfg[n], acc[m][n], 0, 0, 0);
    }
  }

  // epilogue: D layout col = lane&15, row = (lane>>4)*4 + reg  [m89-verified]
  const int lrow = (lane >> 4) * 4;
  const int lcol = lane & 15;
#pragma unroll
  for (int n = 0; n < 4; ++n) {
    const int gcol = colBase + wc * 64 + n * 16 + lcol;
    const float bv = bias[gcol];
#pragma unroll
    for (int m = 0; m < 4; ++m) {
#pragma unroll
      for (int r = 0; r < 4; ++r) {
        const int grow = rowBase + wr * 64 + m * 16 + lrow + r;
        if (grow < M) {
          float v = acc[m][n][r] + bv;
          if (LAYER == 1) {
            v = fmaxf(v, 0.0f);
            outb[grow * DD + gcol] = f2bf(v);
          } else {
            outf[grow * DD + gcol] = v;
          }
        }
      }
    }
  }
}

// ---------------- launch ----------------
extern "C" void kernel_launch(void* const* d_in, const int* in_sizes, int n_in,
                              void* d_out, int out_size, void* d_ws, size_t ws_size,
                              hipStream_t stream) {
  const float* x    = (const float*)d_in[0];
  const int*   ei   = (const int*)d_in[1];
  const float* W1l  = (const float*)d_in[2];
  const float* b1   = (const float*)d_in[3];
  const float* W1r  = (const float*)d_in[4];
  const float* W2l  = (const float*)d_in[5];
  const float* b2   = (const float*)d_in[6];
  const float* W2r  = (const float*)d_in[7];
  float* out = (float*)d_out;

  const int* srcIdx = ei;        // edge_index[0]
  const int* tgtIdx = ei + NE;   // edge_index[1]

  char* ws = (char*)d_ws;
  // workspace layout (bytes)
  int* deg    = (int*)(ws + 0);                       // 200000
  int* off    = (int*)(ws + 200064);                  // 200004
  int* cursor = (int*)(ws + 400128);                  // 200000
  int* col    = (int*)(ws + 600192);                  // 3200000
  u16* x_bf   = (u16*)(ws + 3800192);                 // 25600000
  u16* h_bf   = (u16*)(ws + 29400192);                // 25600000
  u16* agg_bf = (u16*)(ws + 55000192);                // 25600000
  u16* Wc1T   = (u16*)(ws + 80600192);                // 262144
  u16* Wc2T   = (u16*)(ws + 80862336);                // 262144
  // total ~81.1 MB

  hipMemsetAsync(deg, 0, NN * sizeof(int), stream);
  k_histo<<<(NE + 255) / 256, 256, 0, stream>>>(tgtIdx, deg);
  k_scan<<<1, 1024, 0, stream>>>(deg, off, cursor);
  k_fill<<<(NE + 255) / 256, 256, 0, stream>>>(srcIdx, tgtIdx, cursor, col);

  k_f32_to_bf16<<<(NN * DD / 4 + 255) / 256, 256, 0, stream>>>(x, x_bf, NN * DD / 4);
  k_make_wcT<<<512, 256, 0, stream>>>(W1l, W1r, Wc1T);
  k_make_wcT<<<512, 256, 0, stream>>>(W2l, W2r, Wc2T);

  dim3 ggrid((NN + BM - 1) / BM, DD / BN);

  // layer 1
  k_aggregate<<<NN / 4, 256, 0, stream>>>(x_bf, off, col, agg_bf);
  k_gemm_fused<1><<<ggrid, 256, 0, stream>>>(agg_bf, x_bf, Wc1T, b1, h_bf, nullptr, NN);
  // layer 2
  k_aggregate<<<NN / 4, 256, 0, stream>>>(h_bf, off, col, agg_bf);
  k_gemm_fused<2><<<ggrid, 256, 0, stream>>>(agg_bf, h_bf, Wc2T, b2, nullptr, out, NN);
}

// Round 2
// 302.852 us; speedup vs baseline: 1.3373x; 1.3373x over previous
//
#include <hip/hip_runtime.h>
#include <hip/hip_bf16.h>

#define NN 50000
#define NE 800000
#define DD 256
#define KK 512   // concat K for fused GEMM
#define SCAN_NB 49  // ceil(NN/1024)

typedef unsigned short u16;
typedef unsigned int   u32;
typedef __attribute__((ext_vector_type(8))) __bf16 bf16x8;
typedef __attribute__((ext_vector_type(4))) float  f32x4;
typedef __attribute__((ext_vector_type(8))) u16    u16x8;
typedef __attribute__((ext_vector_type(4))) u16    u16x4;

static __device__ __forceinline__ u16 f2bf(float f) {
  u32 u = __float_as_uint(f);
  u32 r = (u + 0x7FFFu + ((u >> 16) & 1u)) >> 16;
  return (u16)r;
}
static __device__ __forceinline__ float bf2f(u16 h) {
  return __uint_as_float(((u32)h) << 16);
}

// ---------------- CSR build ----------------
__global__ void k_histo(const int* __restrict__ tgt, int* __restrict__ deg) {
  int i = blockIdx.x * 256 + threadIdx.x;
  if (i < NE) atomicAdd(&deg[tgt[i]], 1);
}

// two-level scan: phase 1 — per-block (1024 elems) exclusive scan + block sum
__global__ void k_scan1(const int* __restrict__ deg, int* __restrict__ locx,
                        int* __restrict__ bsum) {
  __shared__ int wsum[16];
  const int i = blockIdx.x * 1024 + threadIdx.x;
  const int lane = threadIdx.x & 63, wid = threadIdx.x >> 6;
  int v = (i < NN) ? deg[i] : 0;
  int s = v;
#pragma unroll
  for (int d = 1; d < 64; d <<= 1) {
    int t = __shfl_up(s, d, 64);
    if (lane >= d) s += t;
  }
  if (lane == 63) wsum[wid] = s;
  __syncthreads();
  if (wid == 0) {
    int ws = (lane < 16) ? wsum[lane] : 0;
#pragma unroll
    for (int d = 1; d < 16; d <<= 1) {
      int t = __shfl_up(ws, d, 64);
      if (lane >= d) ws += t;
    }
    if (lane < 16) wsum[lane] = ws;
    if (lane == 15) bsum[blockIdx.x] = ws;
  }
  __syncthreads();
  int excl = s - v + (wid ? wsum[wid - 1] : 0);
  if (i < NN) locx[i] = excl;
}

// phase 2 — 1-wave exclusive scan of 49 block sums
__global__ void k_scan2(const int* __restrict__ bsum, int* __restrict__ boff) {
  const int lane = threadIdx.x;
  int v = (lane < SCAN_NB) ? bsum[lane] : 0;
  int s = v;
#pragma unroll
  for (int d = 1; d < 64; d <<= 1) {
    int t = __shfl_up(s, d, 64);
    if (lane >= d) s += t;
  }
  if (lane < SCAN_NB) boff[lane] = s - v;
}

// phase 3 — add block offsets, write off + cursor
__global__ void k_scan3(const int* __restrict__ locx, const int* __restrict__ boff,
                        int* __restrict__ off, int* __restrict__ cursor) {
  const int i = blockIdx.x * 1024 + threadIdx.x;
  if (i < NN) {
    int o = locx[i] + boff[blockIdx.x];
    off[i] = o;
    cursor[i] = o;
  }
  if (i == 0) off[NN] = NE;
}

__global__ void k_fill(const int* __restrict__ src, const int* __restrict__ tgt,
                       int* __restrict__ cursor, int* __restrict__ col) {
  int i = blockIdx.x * 256 + threadIdx.x;
  if (i < NE) {
    int p = atomicAdd(&cursor[tgt[i]], 1);
    col[p] = src[i];
  }
}

// ---------------- dtype prep ----------------
__global__ void k_f32_to_bf16(const float* __restrict__ in, u16* __restrict__ out, int n4) {
  int i = blockIdx.x * 256 + threadIdx.x;
  if (i >= n4) return;
  const float4 v = *reinterpret_cast<const float4*>(in + i * 4);
  u16x4 o; o.x = f2bf(v.x); o.y = f2bf(v.y); o.z = f2bf(v.z); o.w = f2bf(v.w);
  *reinterpret_cast<u16x4*>(out + i * 4) = o;
}

// WcT[n][k] (bf16, [256][512]): k<256 -> Wl[k][n], else Wr[k-256][n]
__global__ void k_make_wcT(const float* __restrict__ Wl, const float* __restrict__ Wr,
                           u16* __restrict__ WcT) {
  int idx = blockIdx.x * 256 + threadIdx.x;  // 131072 total
  int n = idx >> 9, k = idx & 511;
  float v = (k < DD) ? Wl[k * DD + n] : Wr[(k - DD) * DD + n];
  WcT[idx] = f2bf(v);
}

// ---------------- mean aggregation (CSR) ----------------
// one wave per target node; lane handles 4 contiguous features
__global__ void k_aggregate(const u16* __restrict__ feat, const int* __restrict__ off,
                            const int* __restrict__ col, u16* __restrict__ out) {
  const int wave = threadIdx.x >> 6;
  const int lane = threadIdx.x & 63;
  const int node = blockIdx.x * 4 + wave;
  const int s = off[node], e = off[node + 1];
  const int fo = lane * 4;
  float a0 = 0.f, a1 = 0.f, a2 = 0.f, a3 = 0.f;
  int nxt = (s < e) ? col[s] : 0;
  for (int i = s; i < e; ++i) {
    int cur = nxt;
    if (i + 1 < e) nxt = col[i + 1];
    u16x4 v = *reinterpret_cast<const u16x4*>(feat + cur * DD + fo);
    a0 += bf2f(v.x); a1 += bf2f(v.y); a2 += bf2f(v.z); a3 += bf2f(v.w);
  }
  const float scale = (e > s) ? 1.0f / (float)(e - s) : 0.0f;
  u16x4 o;
  o.x = f2bf(a0 * scale); o.y = f2bf(a1 * scale);
  o.z = f2bf(a2 * scale); o.w = f2bf(a3 * scale);
  *reinterpret_cast<u16x4*>(out + node * DD + fo) = o;
}

// ---------------- fused GEMM: out = [A0|A1] @ Wc + bias (+relu) ----------------
// A0 = agg (M x 256 bf16), A1 = x or h (M x 256 bf16), WcT = (256 x 512 bf16, [n][k])
// LAYER==1: relu, bf16 out; LAYER==2: f32 out
#define BM 128
#define BN 128
#define BK 64

template <int LAYER>
__global__ void k_gemm_fused(const u16* __restrict__ A0, const u16* __restrict__ A1,
                             const u16* __restrict__ WcT, const float* __restrict__ bias,
                             u16* __restrict__ outb, float* __restrict__ outf, int M) {
  __shared__ alignas(16) u16 lA[BM * BK];
  __shared__ alignas(16) u16 lB[BN * BK];
  const int tid = threadIdx.x;
  const int rowBase = blockIdx.x * BM;
  const int colBase = blockIdx.y * BN;
  const int wave = tid >> 6, lane = tid & 63;
  const int wr = wave >> 1, wc = wave & 1;  // 2x2 waves, 64x64 each

  f32x4 acc[4][4] = {};

  const int sr = tid >> 3;          // 0..31 staging row within 32-row group
  const int sc = (tid & 7) * 8;     // bf16 col offset 0..56

  for (int k0 = 0; k0 < KK; k0 += BK) {
    if (k0) __syncthreads();
    const u16* Asrc = (k0 < DD) ? A0 : A1;
    const int kk = k0 & (DD - 1);
    // stage A: 128 x 64 bf16 (XOR-swizzled rows)
#pragma unroll
    for (int it = 0; it < 4; ++it) {
      int row = it * 32 + sr;
      int grow = rowBase + row;
      int gr = (grow < M) ? grow : 0;
      u16x8 v = *reinterpret_cast<const u16x8*>(Asrc + gr * DD + kk + sc);
      int kb = (sc * 2) ^ ((row & 7) << 4);
      *reinterpret_cast<u16x8*>((char*)lA + row * 128 + kb) = v;
    }
    // stage B (BT[n][k]): 128 x 64 bf16
#pragma unroll
    for (int it = 0; it < 4; ++it) {
      int row = it * 32 + sr;  // n within tile
      u16x8 v = *reinterpret_cast<const u16x8*>(WcT + (colBase + row) * KK + k0 + sc);
      int kb = (sc * 2) ^ ((row & 7) << 4);
      *reinterpret_cast<u16x8*>((char*)lB + row * 128 + kb) = v;
    }
    __syncthreads();

#pragma unroll
    for (int ks = 0; ks < 2; ++ks) {
      const int kbyte = ks * 64 + (lane >> 4) * 16;
      bf16x8 af[4], bfg[4];
#pragma unroll
      for (int m = 0; m < 4; ++m) {
        int row = wr * 64 + m * 16 + (lane & 15);
        af[m] = *reinterpret_cast<const bf16x8*>((const char*)lA + row * 128 + (kbyte ^ ((row & 7) << 4)));
      }
#pragma unroll
      for (int n = 0; n < 4; ++n) {
        int row = wc * 64 + n * 16 + (lane & 15);
        bfg[n] = *reinterpret_cast<const bf16x8*>((const char*)lB + row * 128 + (kbyte ^ ((row & 7) << 4)));
      }
#pragma unroll
      for (int m = 0; m < 4; ++m)
#pragma unroll
        for (int n = 0; n < 4; ++n)
          acc[m][n] = __builtin_amdgcn_mfma_f32_16x16x32_bf16(af[m], bfg[n], acc[m][n], 0, 0, 0);
    }
  }

  // epilogue: D layout col = lane&15, row = (lane>>4)*4 + reg  [m89-verified]
  const int lrow = (lane >> 4) * 4;
  const int lcol = lane & 15;
#pragma unroll
  for (int n = 0; n < 4; ++n) {
    const int gcol = colBase + wc * 64 + n * 16 + lcol;
    const float bv = bias[gcol];
#pragma unroll
    for (int m = 0; m < 4; ++m) {
#pragma unroll
      for (int r = 0; r < 4; ++r) {
        const int grow = rowBase + wr * 64 + m * 16 + lrow + r;
        if (grow < M) {
          float v = acc[m][n][r] + bv;
          if (LAYER == 1) {
            v = fmaxf(v, 0.0f);
            outb[grow * DD + gcol] = f2bf(v);
          } else {
            outf[grow * DD + gcol] = v;
          }
        }
      }
    }
  }
}

// ---------------- launch ----------------
extern "C" void kernel_launch(void* const* d_in, const int* in_sizes, int n_in,
                              void* d_out, int out_size, void* d_ws, size_t ws_size,
                              hipStream_t stream) {
  const float* x    = (const float*)d_in[0];
  const int*   ei   = (const int*)d_in[1];
  const float* W1l  = (const float*)d_in[2];
  const float* b1   = (const float*)d_in[3];
  const float* W1r  = (const float*)d_in[4];
  const float* W2l  = (const float*)d_in[5];
  const float* b2   = (const float*)d_in[6];
  const float* W2r  = (const float*)d_in[7];
  float* out = (float*)d_out;

  const int* srcIdx = ei;        // edge_index[0]
  const int* tgtIdx = ei + NE;   // edge_index[1]

  char* ws = (char*)d_ws;
  // workspace layout (bytes)
  int* deg    = (int*)(ws + 0);                       // 200000
  int* off    = (int*)(ws + 200064);                  // 200004
  int* cursor = (int*)(ws + 400128);                  // 200000
  int* col    = (int*)(ws + 600192);                  // 3200000
  u16* x_bf   = (u16*)(ws + 3800192);                 // 25600000
  u16* h_bf   = (u16*)(ws + 29400192);                // 25600000
  u16* agg_bf = (u16*)(ws + 55000192);                // 25600000
  u16* Wc1T   = (u16*)(ws + 80600192);                // 262144
  u16* Wc2T   = (u16*)(ws + 80862336);                // 262144
  int* locx   = (int*)(ws + 81124480);                // 200000
  int* bsum   = (int*)(ws + 81324480);                // 256
  int* boff   = (int*)(ws + 81324736);                // 256
  // total ~81.3 MB

  hipMemsetAsync(deg, 0, NN * sizeof(int), stream);
  k_histo<<<(NE + 255) / 256, 256, 0, stream>>>(tgtIdx, deg);
  k_scan1<<<SCAN_NB, 1024, 0, stream>>>(deg, locx, bsum);
  k_scan2<<<1, 64, 0, stream>>>(bsum, boff);
  k_scan3<<<SCAN_NB, 1024, 0, stream>>>(locx, boff, off, cursor);
  k_fill<<<(NE + 255) / 256, 256, 0, stream>>>(srcIdx, tgtIdx, cursor, col);

  k_f32_to_bf16<<<(NN * DD / 4 + 255) / 256, 256, 0, stream>>>(x, x_bf, NN * DD / 4);
  k_make_wcT<<<512, 256, 0, stream>>>(W1l, W1r, Wc1T);
  k_make_wcT<<<512, 256, 0, stream>>>(W2l, W2r, Wc2T);

  dim3 ggrid((NN + BM - 1) / BM, DD / BN);

  // layer 1
  k_aggregate<<<NN / 4, 256, 0, stream>>>(x_bf, off, col, agg_bf);
  k_gemm_fused<1><<<ggrid, 256, 0, stream>>>(agg_bf, x_bf, Wc1T, b1, h_bf, nullptr, NN);
  // layer 2
  k_aggregate<<<NN / 4, 256, 0, stream>>>(h_bf, off, col, agg_bf);
  k_gemm_fused<2><<<ggrid, 256, 0, stream>>>(agg_bf, h_bf, Wc2T, b2, nullptr, out, NN);
}

// Round 3
// 298.530 us; speedup vs baseline: 1.3567x; 1.0145x over previous
//
#include <hip/hip_runtime.h>
#include <hip/hip_bf16.h>

#define NN 50000
#define NE 800000
#define DD 256
#define KK 512   // concat K for fused GEMM
#define SCAN_NB 49  // ceil(NN/1024)

typedef unsigned short u16;
typedef unsigned int   u32;
typedef __attribute__((ext_vector_type(8))) __bf16 bf16x8;
typedef __attribute__((ext_vector_type(4))) float  f32x4;
typedef __attribute__((ext_vector_type(8))) u16    u16x8;
typedef __attribute__((ext_vector_type(4))) u16    u16x4;

static __device__ __forceinline__ u16 f2bf(float f) {
  u32 u = __float_as_uint(f);
  u32 r = (u + 0x7FFFu + ((u >> 16) & 1u)) >> 16;
  return (u16)r;
}
static __device__ __forceinline__ float bf2f(u16 h) {
  return __uint_as_float(((u32)h) << 16);
}

// ---------------- CSR build ----------------
__global__ void k_histo(const int* __restrict__ tgt, int* __restrict__ deg) {
  int i = blockIdx.x * 256 + threadIdx.x;
  if (i < NE) atomicAdd(&deg[tgt[i]], 1);
}

// two-level scan: phase 1 — per-block (1024 elems) exclusive scan + block sum
__global__ void k_scan1(const int* __restrict__ deg, int* __restrict__ locx,
                        int* __restrict__ bsum) {
  __shared__ int wsum[16];
  const int i = blockIdx.x * 1024 + threadIdx.x;
  const int lane = threadIdx.x & 63, wid = threadIdx.x >> 6;
  int v = (i < NN) ? deg[i] : 0;
  int s = v;
#pragma unroll
  for (int d = 1; d < 64; d <<= 1) {
    int t = __shfl_up(s, d, 64);
    if (lane >= d) s += t;
  }
  if (lane == 63) wsum[wid] = s;
  __syncthreads();
  if (wid == 0) {
    int ws = (lane < 16) ? wsum[lane] : 0;
#pragma unroll
    for (int d = 1; d < 16; d <<= 1) {
      int t = __shfl_up(ws, d, 64);
      if (lane >= d) ws += t;
    }
    if (lane < 16) wsum[lane] = ws;
    if (lane == 15) bsum[blockIdx.x] = ws;
  }
  __syncthreads();
  int excl = s - v + (wid ? wsum[wid - 1] : 0);
  if (i < NN) locx[i] = excl;
}

// phase 2 — 1-wave exclusive scan of 49 block sums
__global__ void k_scan2(const int* __restrict__ bsum, int* __restrict__ boff) {
  const int lane = threadIdx.x;
  int v = (lane < SCAN_NB) ? bsum[lane] : 0;
  int s = v;
#pragma unroll
  for (int d = 1; d < 64; d <<= 1) {
    int t = __shfl_up(s, d, 64);
    if (lane >= d) s += t;
  }
  if (lane < SCAN_NB) boff[lane] = s - v;
}

// phase 3 — add block offsets, write off + cursor
__global__ void k_scan3(const int* __restrict__ locx, const int* __restrict__ boff,
                        int* __restrict__ off, int* __restrict__ cursor) {
  const int i = blockIdx.x * 1024 + threadIdx.x;
  if (i < NN) {
    int o = locx[i] + boff[blockIdx.x];
    off[i] = o;
    cursor[i] = o;
  }
  if (i == 0) off[NN] = NE;
}

__global__ void k_fill(const int* __restrict__ src, const int* __restrict__ tgt,
                       int* __restrict__ cursor, int* __restrict__ col) {
  int i = blockIdx.x * 256 + threadIdx.x;
  if (i < NE) {
    int p = atomicAdd(&cursor[tgt[i]], 1);
    col[p] = src[i];
  }
}

// ---------------- dtype prep ----------------
__global__ void k_f32_to_bf16(const float* __restrict__ in, u16* __restrict__ out, int n4) {
  int i = blockIdx.x * 256 + threadIdx.x;
  if (i >= n4) return;
  const float4 v = *reinterpret_cast<const float4*>(in + i * 4);
  u16x4 o; o.x = f2bf(v.x); o.y = f2bf(v.y); o.z = f2bf(v.z); o.w = f2bf(v.w);
  *reinterpret_cast<u16x4*>(out + i * 4) = o;
}

// WcT[n][k] (bf16, [256][512]) for BOTH layers in one launch:
// blockIdx.x < 512 -> layer1, else layer2
__global__ void k_make_wcT(const float* __restrict__ W1l, const float* __restrict__ W1r,
                           const float* __restrict__ W2l, const float* __restrict__ W2r,
                           u16* __restrict__ Wc1T, u16* __restrict__ Wc2T) {
  int gid = blockIdx.x * 256 + threadIdx.x;  // 262144 total
  int layer = gid >> 17;
  int idx = gid & 131071;
  int n = idx >> 9, k = idx & 511;
  const float* Wl = layer ? W2l : W1l;
  const float* Wr = layer ? W2r : W1r;
  u16* WcT = layer ? Wc2T : Wc1T;
  float v = (k < DD) ? Wl[k * DD + n] : Wr[(k - DD) * DD + n];
  WcT[idx] = f2bf(v);
}

// ---------------- mean aggregation (CSR) ----------------
// one wave per target node; HALF-wave (32 lanes) per edge, 16 B (8 feats)/lane.
// Lanes 0-31 take edges s, s+2, ...; lanes 32-63 take s+1, s+3, ...
__global__ void k_aggregate(const u16* __restrict__ feat, const int* __restrict__ off,
                            const int* __restrict__ col, u16* __restrict__ out) {
  const int wave = threadIdx.x >> 6;
  const int lane = threadIdx.x & 63;
  const int half = lane >> 5;
  const int l32 = lane & 31;
  const int node = blockIdx.x * 4 + wave;
  const int s = off[node], e = off[node + 1];
  const int fo = l32 * 8;  // 8 bf16 = 16 B per lane
  float a[8] = {0.f, 0.f, 0.f, 0.f, 0.f, 0.f, 0.f, 0.f};

  int i = s + half;
  int c = (i < e) ? col[i] : 0;
  for (; i < e; i += 2) {
    int cn = (i + 2 < e) ? col[i + 2] : 0;  // prefetch next col
    u16x8 v = *reinterpret_cast<const u16x8*>(feat + c * DD + fo);
#pragma unroll
    for (int j = 0; j < 8; ++j) a[j] += bf2f(v[j]);
    c = cn;
  }
  // combine halves: lane l += lane l^32
#pragma unroll
  for (int j = 0; j < 8; ++j) a[j] += __shfl_xor(a[j], 32, 64);

  if (half == 0) {
    const float scale = (e > s) ? 1.0f / (float)(e - s) : 0.0f;
    u16x8 o;
#pragma unroll
    for (int j = 0; j < 8; ++j) o[j] = f2bf(a[j] * scale);
    *reinterpret_cast<u16x8*>(out + node * DD + fo) = o;
  }
}

// ---------------- fused GEMM: out = [A0|A1] @ Wc + bias (+relu) ----------------
// A0 = agg (M x 256 bf16), A1 = x or h (M x 256 bf16), WcT = (256 x 512 bf16, [n][k])
// LAYER==1: relu, bf16 out; LAYER==2: f32 out
#define BM 128
#define BN 128
#define BK 64

template <int LAYER>
__global__ void k_gemm_fused(const u16* __restrict__ A0, const u16* __restrict__ A1,
                             const u16* __restrict__ WcT, const float* __restrict__ bias,
                             u16* __restrict__ outb, float* __restrict__ outf, int M) {
  __shared__ alignas(16) u16 lA[BM * BK];
  __shared__ alignas(16) u16 lB[BN * BK];
  const int tid = threadIdx.x;
  const int rowBase = blockIdx.x * BM;
  const int colBase = blockIdx.y * BN;
  const int wave = tid >> 6, lane = tid & 63;
  const int wr = wave >> 1, wc = wave & 1;  // 2x2 waves, 64x64 each

  f32x4 acc[4][4] = {};

  const int sr = tid >> 3;          // 0..31 staging row within 32-row group
  const int sc = (tid & 7) * 8;     // bf16 col offset 0..56

  for (int k0 = 0; k0 < KK; k0 += BK) {
    if (k0) __syncthreads();
    const u16* Asrc = (k0 < DD) ? A0 : A1;
    const int kk = k0 & (DD - 1);
    // stage A: 128 x 64 bf16 (XOR-swizzled rows)
#pragma unroll
    for (int it = 0; it < 4; ++it) {
      int row = it * 32 + sr;
      int grow = rowBase + row;
      int gr = (grow < M) ? grow : 0;
      u16x8 v = *reinterpret_cast<const u16x8*>(Asrc + gr * DD + kk + sc);
      int kb = (sc * 2) ^ ((row & 7) << 4);
      *reinterpret_cast<u16x8*>((char*)lA + row * 128 + kb) = v;
    }
    // stage B (BT[n][k]): 128 x 64 bf16
#pragma unroll
    for (int it = 0; it < 4; ++it) {
      int row = it * 32 + sr;  // n within tile
      u16x8 v = *reinterpret_cast<const u16x8*>(WcT + (colBase + row) * KK + k0 + sc);
      int kb = (sc * 2) ^ ((row & 7) << 4);
      *reinterpret_cast<u16x8*>((char*)lB + row * 128 + kb) = v;
    }
    __syncthreads();

#pragma unroll
    for (int ks = 0; ks < 2; ++ks) {
      const int kbyte = ks * 64 + (lane >> 4) * 16;
      bf16x8 af[4], bfg[4];
#pragma unroll
      for (int m = 0; m < 4; ++m) {
        int row = wr * 64 + m * 16 + (lane & 15);
        af[m] = *reinterpret_cast<const bf16x8*>((const char*)lA + row * 128 + (kbyte ^ ((row & 7) << 4)));
      }
#pragma unroll
      for (int n = 0; n < 4; ++n) {
        int row = wc * 64 + n * 16 + (lane & 15);
        bfg[n] = *reinterpret_cast<const bf16x8*>((const char*)lB + row * 128 + (kbyte ^ ((row & 7) << 4)));
      }
#pragma unroll
      for (int m = 0; m < 4; ++m)
#pragma unroll
        for (int n = 0; n < 4; ++n)
          acc[m][n] = __builtin_amdgcn_mfma_f32_16x16x32_bf16(af[m], bfg[n], acc[m][n], 0, 0, 0);
    }
  }

  // epilogue: D layout col = lane&15, row = (lane>>4)*4 + reg  [m89-verified]
  const int lrow = (lane >> 4) * 4;
  const int lcol = lane & 15;
#pragma unroll
  for (int n = 0; n < 4; ++n) {
    const int gcol = colBase + wc * 64 + n * 16 + lcol;
    const float bv = bias[gcol];
#pragma unroll
    for (int m = 0; m < 4; ++m) {
#pragma unroll
      for (int r = 0; r < 4; ++r) {
        const int grow = rowBase + wr * 64 + m * 16 + lrow + r;
        if (grow < M) {
          float v = acc[m][n][r] + bv;
          if (LAYER == 1) {
            v = fmaxf(v, 0.0f);
            outb[grow * DD + gcol] = f2bf(v);
          } else {
            outf[grow * DD + gcol] = v;
          }
        }
      }
    }
  }
}

// ---------------- launch ----------------
extern "C" void kernel_launch(void* const* d_in, const int* in_sizes, int n_in,
                              void* d_out, int out_size, void* d_ws, size_t ws_size,
                              hipStream_t stream) {
  const float* x    = (const float*)d_in[0];
  const int*   ei   = (const int*)d_in[1];
  const float* W1l  = (const float*)d_in[2];
  const float* b1   = (const float*)d_in[3];
  const float* W1r  = (const float*)d_in[4];
  const float* W2l  = (const float*)d_in[5];
  const float* b2   = (const float*)d_in[6];
  const float* W2r  = (const float*)d_in[7];
  float* out = (float*)d_out;

  const int* srcIdx = ei;        // edge_index[0]
  const int* tgtIdx = ei + NE;   // edge_index[1]

  char* ws = (char*)d_ws;
  // workspace layout (bytes)
  int* deg    = (int*)(ws + 0);                       // 200000
  int* off    = (int*)(ws + 200064);                  // 200004
  int* cursor = (int*)(ws + 400128);                  // 200000
  int* col    = (int*)(ws + 600192);                  // 3200000
  u16* x_bf   = (u16*)(ws + 3800192);                 // 25600000
  u16* h_bf   = (u16*)(ws + 29400192);                // 25600000
  u16* agg_bf = (u16*)(ws + 55000192);                // 25600000
  u16* Wc1T   = (u16*)(ws + 80600192);                // 262144
  u16* Wc2T   = (u16*)(ws + 80862336);                // 262144
  int* locx   = (int*)(ws + 81124480);                // 200000
  int* bsum   = (int*)(ws + 81324480);                // 256
  int* boff   = (int*)(ws + 81324736);                // 256
  // total ~81.3 MB

  hipMemsetAsync(deg, 0, NN * sizeof(int), stream);
  k_histo<<<(NE + 255) / 256, 256, 0, stream>>>(tgtIdx, deg);
  k_scan1<<<SCAN_NB, 1024, 0, stream>>>(deg, locx, bsum);
  k_scan2<<<1, 64, 0, stream>>>(bsum, boff);
  k_scan3<<<SCAN_NB, 1024, 0, stream>>>(locx, boff, off, cursor);
  k_fill<<<(NE + 255) / 256, 256, 0, stream>>>(srcIdx, tgtIdx, cursor, col);

  k_f32_to_bf16<<<(NN * DD / 4 + 255) / 256, 256, 0, stream>>>(x, x_bf, NN * DD / 4);
  k_make_wcT<<<1024, 256, 0, stream>>>(W1l, W1r, W2l, W2r, Wc1T, Wc2T);

  dim3 ggrid((NN + BM - 1) / BM, DD / BN);

  // layer 1
  k_aggregate<<<NN / 4, 256, 0, stream>>>(x_bf, off, col, agg_bf);
  k_gemm_fused<1><<<ggrid, 256, 0, stream>>>(agg_bf, x_bf, Wc1T, b1, h_bf, nullptr, NN);
  // layer 2
  k_aggregate<<<NN / 4, 256, 0, stream>>>(h_bf, off, col, agg_bf);
  k_gemm_fused<2><<<ggrid, 256, 0, stream>>>(agg_bf, h_bf, Wc2T, b2, nullptr, out, NN);
}